// Round 1
// 277.674 us; speedup vs baseline: 1.0613x; 1.0613x over previous
//
#include <hip/hip_runtime.h>
#include <hip/hip_bf16.h>
#include <math.h>

// Problem constants (match reference)
#define BATCH   131072
#define FEAT    256
#define NCLASS  50000
#define EPS     1e-12f
#define LAMBDA  0.5f
#define CAP     32      // fallback-path bucket capacity

constexpr int WPB     = 4;                    // waves per 256-thread block
constexpr int NBLK_SS = NCLASS / WPB;         // 12500
constexpr int NSCAN   = (NCLASS + 255) / 256; // 196

// Fast-path ws layout (4B units):
//   cnt[NCLASS] | cursor[NCLASS] | bsum[256] | boff[256] | pB[NBLK_SS] | sIdx[BATCH]
// d_out: out[0]=loss ; out[1..] = new_centers.
//
// v2 design: no bf16 sorted-feature round-trip. We sort only ROW INDICES by
// class (0.5 MB), then the segmented-sum kernel gathers fp32 feature rows
// directly (1 KB contiguous per row, coalesced) and computes the L2 norm
// in-wave. Cuts HBM traffic ~374 MB -> ~240 MB and removes one big kernel.

__device__ __forceinline__ float wave_reduce_sum(float v) {
    #pragma unroll
    for (int m = 32; m; m >>= 1) v += __shfl_xor(v, m, 64);
    return v;
}

// ---- histogram ----
__global__ __launch_bounds__(256) void histo(const int* __restrict__ labels,
                                             int* __restrict__ cnt) {
    const int i = blockIdx.x * 256 + threadIdx.x;
    atomicAdd(&cnt[labels[i]], 1);
}

// ---- multi-block exclusive scan of cnt -> cursor ----
__global__ __launch_bounds__(256) void scan_bsum(const int* __restrict__ cnt,
                                                 int* __restrict__ bsum) {
    __shared__ int s[256];
    const int i = blockIdx.x * 256 + threadIdx.x;
    s[threadIdx.x] = (i < NCLASS) ? cnt[i] : 0;
    __syncthreads();
    for (int off = 128; off; off >>= 1) {
        if (threadIdx.x < off) s[threadIdx.x] += s[threadIdx.x + off];
        __syncthreads();
    }
    if (threadIdx.x == 0) bsum[blockIdx.x] = s[0];
}

__global__ __launch_bounds__(256) void scan_boff(const int* __restrict__ bsum,
                                                 int* __restrict__ boff) {
    __shared__ int s[256];
    const int t = threadIdx.x;
    const int v = (t < NSCAN) ? bsum[t] : 0;
    s[t] = v;
    __syncthreads();
    for (int off = 1; off < 256; off <<= 1) {
        int u = (t >= off) ? s[t - off] : 0;
        __syncthreads();
        s[t] += u;
        __syncthreads();
    }
    if (t < NSCAN) boff[t] = s[t] - v;
}

__global__ __launch_bounds__(256) void scan_final(const int* __restrict__ cnt,
                                                  const int* __restrict__ boff,
                                                  int* __restrict__ cursor) {
    __shared__ int s[256];
    const int t = threadIdx.x;
    const int i = blockIdx.x * 256 + t;
    const int v = (i < NCLASS) ? cnt[i] : 0;
    s[t] = v;
    __syncthreads();
    for (int off = 1; off < 256; off <<= 1) {
        int u = (t >= off) ? s[t - off] : 0;
        __syncthreads();
        s[t] += u;
        __syncthreads();
    }
    if (i < NCLASS) cursor[i] = s[t] - v + boff[blockIdx.x];
}

// ---- scatter row indices into class-sorted order (0.5 MB, trivial) ----
__global__ __launch_bounds__(256) void scatter_idx(const int* __restrict__ labels,
                                                   int* __restrict__ cursor,  // advanced to end
                                                   int* __restrict__ sIdx) {
    const int i = blockIdx.x * 256 + threadIdx.x;
    const int slot = atomicAdd(&cursor[labels[i]], 1);
    sIdx[slot] = i;
}

// ---- fused: gather fp32 rows per class, normalize in-wave, segmented sum,
//      center update, loss partial ----
__global__ __launch_bounds__(256) void segsum_gather(
        const float* __restrict__ feat,
        const float* __restrict__ centers,
        const int*   __restrict__ cnt,
        const int*   __restrict__ cursor_end,   // end offsets (post-scatter)
        const int*   __restrict__ sIdx,
        float*       __restrict__ outc,         // = out+1
        float*       __restrict__ pB) {
    const int wave = threadIdx.x >> 6;
    const int lane = threadIdx.x & 63;
    const int c    = blockIdx.x * WPB + wave;   // < NCLASS exactly

    const int n     = cnt[c];
    const int start = cursor_end[c] - n;

    float4 acc   = {0.f, 0.f, 0.f, 0.f};
    float  fsum2 = 0.f;   // sum over rows of ||f||^2 (wave-uniform)

    for (int base = 0; base < n; base += 64) {
        const int cn = min(64, n - base);
        int myidx = 0;
        if (lane < cn) myidx = sIdx[start + base + lane];

        for (int s = 0; s < cn; s += 4) {
            const int m  = cn - s;                       // wave-uniform
            const int r0 = __shfl(myidx, s + 0, 64);
            const int r1 = __shfl(myidx, s + 1, 64);
            const int r2 = __shfl(myidx, s + 2, 64);
            const int r3 = __shfl(myidx, s + 3, 64);

            const float4 v0 = ((const float4*)(feat + (size_t)r0 * FEAT))[lane];
            float4 v1 = {0.f,0.f,0.f,0.f}, v2 = {0.f,0.f,0.f,0.f}, v3 = {0.f,0.f,0.f,0.f};
            if (m > 1) v1 = ((const float4*)(feat + (size_t)r1 * FEAT))[lane];
            if (m > 2) v2 = ((const float4*)(feat + (size_t)r2 * FEAT))[lane];
            if (m > 3) v3 = ((const float4*)(feat + (size_t)r3 * FEAT))[lane];

            float a0 = v0.x*v0.x + v0.y*v0.y + v0.z*v0.z + v0.w*v0.w;
            float a1 = v1.x*v1.x + v1.y*v1.y + v1.z*v1.z + v1.w*v1.w;
            float a2 = v2.x*v2.x + v2.y*v2.y + v2.z*v2.z + v2.w*v2.w;
            float a3 = v3.x*v3.x + v3.y*v3.y + v3.z*v3.z + v3.w*v3.w;

            // 4 independent butterfly reductions, interleaved for ILP
            #pragma unroll
            for (int sh = 32; sh; sh >>= 1) {
                a0 += __shfl_xor(a0, sh, 64);
                a1 += __shfl_xor(a1, sh, 64);
                a2 += __shfl_xor(a2, sh, 64);
                a3 += __shfl_xor(a3, sh, 64);
            }

            const float i0 = 1.0f / fmaxf(sqrtf(a0), EPS);
            const float i1 = 1.0f / fmaxf(sqrtf(a1), EPS);
            const float i2 = 1.0f / fmaxf(sqrtf(a2), EPS);
            const float i3 = 1.0f / fmaxf(sqrtf(a3), EPS);

            acc.x += v0.x*i0 + v1.x*i1 + v2.x*i2 + v3.x*i3;
            acc.y += v0.y*i0 + v1.y*i1 + v2.y*i2 + v3.y*i3;
            acc.z += v0.z*i0 + v1.z*i1 + v2.z*i2 + v3.z*i3;
            acc.w += v0.w*i0 + v1.w*i1 + v2.w*i2 + v3.w*i3;

            // padded rows: a==0 -> (0*i)*i == 0, no inf/nan
            fsum2 += (a0*i0)*i0 + (a1*i1)*i1 + (a2*i2)*i2 + (a3*i3)*i3;
        }
    }

    const float4 cv = ((const float4*)(centers + (size_t)c * FEAT))[lane];
    const float fn = (float)n;
    const float w  = 1.0f / (1.0f + fn);

    float4 nc;
    nc.x = cv.x - LAMBDA * (fn * cv.x - acc.x) * w;
    nc.y = cv.y - LAMBDA * (fn * cv.y - acc.y) * w;
    nc.z = cv.z - LAMBDA * (fn * cv.z - acc.z) * w;
    nc.w = cv.w - LAMBDA * (fn * cv.w - acc.w) * w;
    ((float4*)(outc + (size_t)c * FEAT))[lane] = nc;

    // loss partial: n*||c||^2 - 2*acc.c  (per-lane 4 dims), + sum ||f||^2
    float lp = fn * (cv.x*cv.x + cv.y*cv.y + cv.z*cv.z + cv.w*cv.w)
             - 2.0f * (acc.x*cv.x + acc.y*cv.y + acc.z*cv.z + acc.w*cv.w);
    lp = wave_reduce_sum(lp);

    __shared__ float red[WPB];
    if (lane == 0) red[wave] = lp + fsum2;
    __syncthreads();
    if (threadIdx.x == 0)
        pB[blockIdx.x] = red[0] + red[1] + red[2] + red[3];
}

// ---- final loss reduction ----
__global__ __launch_bounds__(1024) void finish(const float* __restrict__ pB,
                                               float* __restrict__ out0) {
    float s = 0.0f;
    for (int i = threadIdx.x; i < NBLK_SS; i += 1024) s += pB[i];
    s = wave_reduce_sum(s);
    __shared__ float red[16];
    const int wave = threadIdx.x >> 6;
    const int lane = threadIdx.x & 63;
    if (lane == 0) red[wave] = s;
    __syncthreads();
    if (threadIdx.x == 0) {
        float t = 0.0f;
        #pragma unroll
        for (int i = 0; i < 16; ++i) t += red[i];
        out0[0] = t * (1.0f / (float)BATCH);
    }
}

// ================= fallback path (bucket gather) =================

__global__ __launch_bounds__(256) void scatter_bucket(const int* __restrict__ labels,
                                                      int* __restrict__ cnt,
                                                      int* __restrict__ bucket) {
    const int i = blockIdx.x * 256 + threadIdx.x;
    const int c = labels[i];
    const int slot = atomicAdd(&cnt[c], 1);
    if (slot < CAP) bucket[c * CAP + slot] = i;
}

__global__ __launch_bounds__(256) void gather_bucket(
        const float* __restrict__ feat, const float* __restrict__ centers,
        const int* __restrict__ cnt, const int* __restrict__ bucket,
        float* __restrict__ outc, float* __restrict__ pB) {
    const int wave = threadIdx.x >> 6;
    const int lane = threadIdx.x & 63;
    const int c    = blockIdx.x * WPB + wave;
    const int n = min(cnt[c], CAP);
    const int myidx = (lane < n) ? bucket[c * CAP + lane] : 0;
    float4 acc = {0.f,0.f,0.f,0.f};
    float fsum2 = 0.f;
    for (int s = 0; s < n; ++s) {
        const int r = __shfl(myidx, s, 64);
        const float4 v = ((const float4*)(feat + (size_t)r * FEAT))[lane];
        float ss = wave_reduce_sum(v.x*v.x + v.y*v.y + v.z*v.z + v.w*v.w);
        const float rinv = 1.0f / fmaxf(sqrtf(ss), EPS);
        acc.x += v.x*rinv; acc.y += v.y*rinv; acc.z += v.z*rinv; acc.w += v.w*rinv;
        fsum2 += ss * rinv * rinv;
    }
    const float4 cv = ((const float4*)(centers + (size_t)c * FEAT))[lane];
    const float fn = (float)n;
    const float w  = 1.0f / (1.0f + fn);
    float4 nc;
    nc.x = cv.x - LAMBDA * (fn*cv.x - acc.x) * w;
    nc.y = cv.y - LAMBDA * (fn*cv.y - acc.y) * w;
    nc.z = cv.z - LAMBDA * (fn*cv.z - acc.z) * w;
    nc.w = cv.w - LAMBDA * (fn*cv.w - acc.w) * w;
    ((float4*)(outc + (size_t)c * FEAT))[lane] = nc;
    float lp = fn * (cv.x*cv.x + cv.y*cv.y + cv.z*cv.z + cv.w*cv.w)
             - 2.0f * (acc.x*cv.x + acc.y*cv.y + acc.z*cv.z + acc.w*cv.w);
    lp = wave_reduce_sum(lp);
    __shared__ float red[WPB];
    if (lane == 0) red[wave] = lp + fsum2;
    __syncthreads();
    if (threadIdx.x == 0)
        pB[blockIdx.x] = red[0] + red[1] + red[2] + red[3];
}

__global__ __launch_bounds__(1024) void finishB(const float* __restrict__ pB,
                                                float* __restrict__ out0) {
    float s = 0.0f;
    for (int i = threadIdx.x; i < NBLK_SS; i += 1024) s += pB[i];
    s = wave_reduce_sum(s);
    __shared__ float red[16];
    const int wave = threadIdx.x >> 6;
    const int lane = threadIdx.x & 63;
    if (lane == 0) red[wave] = s;
    __syncthreads();
    if (threadIdx.x == 0) {
        float t = 0.0f;
        #pragma unroll
        for (int i = 0; i < 16; ++i) t += red[i];
        out0[0] = t * (1.0f / (float)BATCH);
    }
}

extern "C" void kernel_launch(void* const* d_in, const int* in_sizes, int n_in,
                              void* d_out, int out_size, void* d_ws, size_t ws_size,
                              hipStream_t stream) {
    const float* feat    = (const float*)d_in[0];
    const int*   labels  = (const int*)  d_in[1];
    const float* centers = (const float*)d_in[2];
    float* out = (float*)d_out;

    // fast path needs: cnt + cursor + bsum + boff + pB + sIdx  (~976 KB)
    const size_t need_fast = ((size_t)NCLASS * 2 + 512 + NBLK_SS + BATCH) * 4;

    if (ws_size >= need_fast) {
        int*   cnt    = (int*)d_ws;
        int*   cursor = cnt + NCLASS;
        int*   bsum   = cursor + NCLASS;
        int*   boff   = bsum + 256;
        float* pB     = (float*)(boff + 256);
        int*   sIdx   = (int*)(pB + NBLK_SS);

        hipMemsetAsync(cnt, 0, NCLASS * sizeof(int), stream);
        histo      <<<BATCH / 256, 256, 0, stream>>>(labels, cnt);
        scan_bsum  <<<NSCAN, 256, 0, stream>>>(cnt, bsum);
        scan_boff  <<<1, 256, 0, stream>>>(bsum, boff);
        scan_final <<<NSCAN, 256, 0, stream>>>(cnt, boff, cursor);
        scatter_idx<<<BATCH / 256, 256, 0, stream>>>(labels, cursor, sIdx);
        segsum_gather<<<NBLK_SS, 256, 0, stream>>>(feat, centers, cnt, cursor,
                                                   sIdx, out + 1, pB);
        finish<<<1, 1024, 0, stream>>>(pB, out);
    } else {
        int*   cnt    = (int*)d_ws;
        int*   bucket = cnt + NCLASS;
        float* pB     = (float*)(bucket + (size_t)NCLASS * CAP);
        hipMemsetAsync(cnt, 0, NCLASS * sizeof(int), stream);
        scatter_bucket<<<BATCH / 256, 256, 0, stream>>>(labels, cnt, bucket);
        gather_bucket <<<NBLK_SS, 256, 0, stream>>>(feat, centers, cnt, bucket,
                                                    out + 1, pB);
        finishB<<<1, 1024, 0, stream>>>(pB, out);
    }
}